// Round 1
// baseline (124.107 us; speedup 1.0000x reference)
//
#include <hip/hip_runtime.h>
#include <stdint.h>

#define CIN   4
#define LEN   2048
#define HN    256
#define GL    24
#define LOUT  2025          // LEN - GL + 1
#define XP    2080          // padded LDS row stride in halfwords (mult of 8, >= 2048+32)

typedef short  s16x8 __attribute__((ext_vector_type(8)));
typedef float  f32x4 __attribute__((ext_vector_type(4)));

static __device__ __forceinline__ uint16_t f2bf(float f) {
    union { float f; uint32_t u; } v; v.f = f;
    uint32_t u = v.u;
    return (uint16_t)((u + 0x7FFFu + ((u >> 16) & 1u)) >> 16);   // RNE
}

// ---------------------------------------------------------------------------
// Kernel 1: per-sample conv1d (bf16 MFMA) + bias + relu + max/avg pool, fused.
// grid = 256 blocks (1 sample each), 512 threads = 8 waves.
// Wave w handles nodes [32w, 32w+32) (2 n-subtiles), all 2048 padded positions.
// Positions are phase-strided: t = p + 8*(16j + m), p=0..7 phase, j=0..15,
// m = A-fragment row (lane&15). Pooling is order-invariant so this is exact.
// ---------------------------------------------------------------------------
__global__ __launch_bounds__(512, 2) void conv_pool_kernel(
    const float* __restrict__ x, const float* __restrict__ wConv,
    const float* __restrict__ wRect, float* __restrict__ pool)
{
    __shared__ uint16_t xs[CIN * XP];          // 16640 B, bf16 x for this sample

    const int tid  = threadIdx.x;
    const int b    = blockIdx.x;
    const int lane = tid & 63;
    const int wid  = tid >> 6;                 // 0..7
    const int n    = lane & 15;                // MFMA row (A) / col (B,C)
    const int q    = lane >> 4;                // quad 0..3

    // ---- stage x[b] -> LDS as bf16 (coalesced float4 loads) ----
    const float* xb = x + (size_t)b * (CIN * LEN);
    #pragma unroll
    for (int it = 0; it < 4; ++it) {
        int i = (tid + it * 512) * 4;          // 0..8188 step 4
        float4 v = *(const float4*)(xb + i);
        int c = i >> 11, off = i & 2047;
        uint64_t pk =  (uint64_t)f2bf(v.x)
                    | ((uint64_t)f2bf(v.y) << 16)
                    | ((uint64_t)f2bf(v.z) << 32)
                    | ((uint64_t)f2bf(v.w) << 48);
        *(uint64_t*)&xs[c * XP + off] = pk;
    }
    // zero the pad tail [2048, 2080) of each row
    if (tid < 64) {
        int c = tid >> 4, o = (tid & 15) * 2;
        *(uint32_t*)&xs[c * XP + 2048 + o] = 0u;
    }

    // ---- resident B fragments (weights) + bias, straight from global ----
    // B[k][n]: n = lane&15 -> node h0+n ; quad q -> k-8block jb = 4*ks + q
    // jb -> (c = jb/3, g0 = 8*(jb%3)); w[h][c][g0..g0+8) contiguous fp32.
    s16x8 bfrag[2][3];
    float negb[2];
    #pragma unroll
    for (int s = 0; s < 2; ++s) {
        int h = wid * 32 + s * 16 + n;
        negb[s] = -wRect[h];
        #pragma unroll
        for (int ks = 0; ks < 3; ++ks) {
            int jb = ks * 4 + q;
            const float* wp = wConv + h * (CIN * GL) + jb * 8;
            float4 w0 = *(const float4*)(wp);
            float4 w1 = *(const float4*)(wp + 4);
            s16x8 f;
            f[0]=(short)f2bf(w0.x); f[1]=(short)f2bf(w0.y);
            f[2]=(short)f2bf(w0.z); f[3]=(short)f2bf(w0.w);
            f[4]=(short)f2bf(w1.x); f[5]=(short)f2bf(w1.y);
            f[6]=(short)f2bf(w1.z); f[7]=(short)f2bf(w1.w);
            bfrag[s][ks] = f;
        }
    }

    // per-lane A base (halfword index): all terms mult of 8 -> 16B aligned
    int abase[3];
    #pragma unroll
    for (int ks = 0; ks < 3; ++ks) {
        int jb = ks * 4 + q;
        int c = jb / 3, g0 = (jb % 3) * 8;
        abase[ks] = c * XP + g0 + 8 * n;
    }

    __syncthreads();

    float rawmax[2] = {-1e30f, -1e30f};
    float sums[2]   = {0.f, 0.f};

    #pragma unroll 1
    for (int j = 0; j < 16; ++j) {
        f32x4 acc[8][2];
        #pragma unroll
        for (int ks = 0; ks < 3; ++ks) {
            // one aligned 32B window covers fragments of ALL 8 phases
            const uint4 r0 = *(const uint4*)&xs[abase[ks] + 128 * j];
            const uint4 r1 = *(const uint4*)&xs[abase[ks] + 128 * j + 8];
            uint32_t d[8] = {r0.x, r0.y, r0.z, r0.w, r1.x, r1.y, r1.z, r1.w};
            #pragma unroll
            for (int p = 0; p < 8; ++p) {
                uint32_t f0, f1, f2, f3;
                if ((p & 1) == 0) {
                    f0 = d[p/2]; f1 = d[p/2+1]; f2 = d[p/2+2]; f3 = d[p/2+3];
                } else {
                    f0 = __builtin_amdgcn_alignbit(d[(p+1)/2],   d[(p-1)/2],   16);
                    f1 = __builtin_amdgcn_alignbit(d[(p+1)/2+1], d[(p-1)/2+1], 16);
                    f2 = __builtin_amdgcn_alignbit(d[(p+1)/2+2], d[(p-1)/2+2], 16);
                    f3 = __builtin_amdgcn_alignbit(d[(p+1)/2+3], d[(p-1)/2+3], 16);
                }
                uint4 fu = {f0, f1, f2, f3};
                s16x8 afrag = __builtin_bit_cast(s16x8, fu);
                #pragma unroll
                for (int s = 0; s < 2; ++s) {
                    f32x4 cin = (ks == 0) ? (f32x4){0.f, 0.f, 0.f, 0.f} : acc[p][s];
                    acc[p][s] = __builtin_amdgcn_mfma_f32_16x16x32_bf16(
                        afrag, bfrag[s][ks], cin, 0, 0, 0);
                }
            }
        }
        // ---- fold: relu(v+b) = max(v,-b)+b ; bias deferred out of loop ----
        if (j < 15) {                       // all positions valid (t <= 1951)
            #pragma unroll
            for (int p = 0; p < 8; ++p)
                #pragma unroll
                for (int s = 0; s < 2; ++s)
                    #pragma unroll
                    for (int r = 0; r < 4; ++r) {
                        float t = fmaxf(acc[p][s][r], negb[s]);
                        sums[s]   += t;
                        rawmax[s]  = fmaxf(rawmax[s], t);
                    }
        } else {                            // tail: mask t >= 2025
            #pragma unroll
            for (int p = 0; p < 8; ++p)
                #pragma unroll
                for (int s = 0; s < 2; ++s)
                    #pragma unroll
                    for (int r = 0; r < 4; ++r) {
                        int tpos = p + 128 * 15 + 32 * q + 8 * r;
                        float t = (tpos < LOUT) ? fmaxf(acc[p][s][r], negb[s])
                                                : negb[s];   // contributes exactly 0 after +b
                        sums[s]   += t;
                        rawmax[s]  = fmaxf(rawmax[s], t);
                    }
        }
    }

    // ---- cross-quad reduce (lanes n, n+16, n+32, n+48) and write pool ----
    #pragma unroll
    for (int s = 0; s < 2; ++s) {
        float m  = rawmax[s], sm = sums[s];
        m  = fmaxf(m, __shfl_xor(m, 16, 64));  sm += __shfl_xor(sm, 16, 64);
        m  = fmaxf(m, __shfl_xor(m, 32, 64));  sm += __shfl_xor(sm, 32, 64);
        if (q == 0) {
            int h = wid * 32 + s * 16 + n;
            float bia = -negb[s];
            // maxPool = max(0, b + max_t v) ; avgPool = (sum_all + 2048*b)/2025
            pool[(size_t)b * 512 + h]       = fmaxf(m + bia, 0.f);
            pool[(size_t)b * 512 + 256 + h] = (sm + 2048.f * bia) * (1.0f / 2025.0f);
        }
    }
}

// ---------------------------------------------------------------------------
// Kernel 2: fp32 MLP. hid = relu(pool @ wH + bH); out = 0.5*hid@wNeu + bias.
// grid = 256 blocks: 8 output-groups (64 outs) x 32 sample-groups (8 samples).
// 256 threads: o = og*64 + (tid&63); wave wv handles samples wv*2, wv*2+1.
// Partial dot wave-reduced, atomicAdd into zeroed d_out.
// ---------------------------------------------------------------------------
__global__ __launch_bounds__(256, 4) void mlp_kernel(
    const float* __restrict__ pool, const float* __restrict__ wH,
    const float* __restrict__ bH, const float* __restrict__ wNeu,
    const float* __restrict__ wNeuB, float* __restrict__ out)
{
    __shared__ float pl[8][512];               // 16 KB

    const int tid = threadIdx.x;
    const int og  = blockIdx.x & 7;
    const int bg  = blockIdx.x >> 3;
    const int o   = og * 64 + (tid & 63);
    const int wv  = tid >> 6;                  // wave id -> samples wv*2 + {0,1}

    const float* ps = pool + (size_t)bg * 8 * 512;
    #pragma unroll
    for (int it = 0; it < 4; ++it) {
        int i = (tid + it * 256) * 4;          // 0..4095
        *(float4*)&pl[0][i] = *(const float4*)(ps + i);
    }
    __syncthreads();

    float acc0 = 0.f, acc1 = 0.f;
    const float* prow0 = &pl[wv * 2][0];       // wave-uniform -> LDS broadcast
    const float* prow1 = &pl[wv * 2 + 1][0];
    #pragma unroll 4
    for (int i = 0; i < 512; i += 4) {
        float4 p0 = *(const float4*)(prow0 + i);
        float4 p1 = *(const float4*)(prow1 + i);
        float w0 = wH[(i + 0) * 512 + o];      // lanes consecutive -> coalesced
        float w1 = wH[(i + 1) * 512 + o];
        float w2 = wH[(i + 2) * 512 + o];
        float w3 = wH[(i + 3) * 512 + o];
        acc0 = fmaf(p0.x, w0, acc0); acc0 = fmaf(p0.y, w1, acc0);
        acc0 = fmaf(p0.z, w2, acc0); acc0 = fmaf(p0.w, w3, acc0);
        acc1 = fmaf(p1.x, w0, acc1); acc1 = fmaf(p1.y, w1, acc1);
        acc1 = fmaf(p1.z, w2, acc1); acc1 = fmaf(p1.w, w3, acc1);
    }
    float hb  = bH[o];
    float wn  = wNeu[o];
    float v0  = fmaxf(acc0 + hb, 0.f) * wn;
    float v1  = fmaxf(acc1 + hb, 0.f) * wn;
    #pragma unroll
    for (int dlt = 1; dlt < 64; dlt <<= 1) {
        v0 += __shfl_xor(v0, dlt, 64);
        v1 += __shfl_xor(v1, dlt, 64);
    }
    if ((tid & 63) == 0) {
        int b0 = bg * 8 + wv * 2;
        float bias = (og == 0) ? wNeuB[0] : 0.f;
        atomicAdd(&out[b0],     0.5f * v0 + bias);
        atomicAdd(&out[b0 + 1], 0.5f * v1 + bias);
    }
}

extern "C" void kernel_launch(void* const* d_in, const int* in_sizes, int n_in,
                              void* d_out, int out_size, void* d_ws, size_t ws_size,
                              hipStream_t stream) {
    const float* x        = (const float*)d_in[0];
    const float* wConv    = (const float*)d_in[1];
    const float* wRect    = (const float*)d_in[2];
    const float* wHidden  = (const float*)d_in[3];
    const float* wHidBias = (const float*)d_in[4];
    const float* wNeu     = (const float*)d_in[5];
    const float* wNeuBias = (const float*)d_in[6];
    float* out  = (float*)d_out;
    float* pool = (float*)d_ws;                 // 256*512*4 = 512 KB scratch

    hipMemsetAsync(d_out, 0, 256 * sizeof(float), stream);
    conv_pool_kernel<<<256, 512, 0, stream>>>(x, wConv, wRect, pool);
    mlp_kernel<<<256, 256, 0, stream>>>(pool, wHidden, wHidBias, wNeu, wNeuBias, out);
}